// Round 12
// baseline (77.404 us; speedup 1.0000x reference)
//
#include <hip/hip_runtime.h>
#include <hip/hip_bf16.h>
#include <cstdint>

// STFT via radix-2 split GEMM.
//   C[f,t] = sum_n W[n] x[t*256+n] e^{-2pi i f n/1024}
//   n=2j:   E[f] = sum_j W[2j]  x_e[t*128+j] e^{-2pi i f j/512}
//   n=2j+1: O~[f]= sum_j W[2j+1]x_o[t*128+j] e^{-2pi i f(2j+1)/1024}  (twiddle folded)
//   C[f] = E[f] + O~[f];   C[512-f] = conj(E[f] - O~[f])     f = 0..255
//   A_E rows = kern[.][even cols], A_O~ rows = kern[.][odd cols]  (pure gathers)
// Main GEMM: 1024 A-rows (32-row super-groups: [16 E rows | 16 O~ rows], rows
// within = 2f+ri pairs for 8 bins), K=512, BK=32, BM=256 x BN=256, 256 blocks
// (1/CU), 8 waves of 128x64. 2-slot LDS ring (48KB/slot), stage-1-ahead via
// global_load_lds, one barrier per K-tile (R9 discipline), 64B-row swizzle
// q^(((q>>7)&3)<<4) (measured 0 conflicts). Butterfly epilogue writes f and
// 512-f. Edge kernel (f32 direct): f=256 all t, and t=1024 all f.

#define HOP 256
#define NFFT 1024
#define FB 513
#define NT 1025
#define NBATCH 16
#define SIGLEN 262144
#define HSIG 131584          // SIGP/2 = half-rate padded length
#define BK 32
#define NKT 16               // K tiles (512 / 32)
#define A_BYTES 16384        // 256 rows * 64B
#define SLOT_BYTES (3 * A_BYTES)   // A + Be + Bo = 48 KB
#define LDS_BYTES (2 * SLOT_BYTES) // 96 KB

typedef __attribute__((ext_vector_type(8))) short short8;
typedef __attribute__((ext_vector_type(4))) float f32x4;
typedef unsigned int u32;

__device__ __forceinline__ unsigned short f2bf(float f) {
  u32 u = __float_as_uint(f);
  u = (u + 0x7FFFu + ((u >> 16) & 1u)) >> 16;   // RNE
  return (unsigned short)u;
}

// ---- fused prologue ----
// blocks [0, 256):  A2[r][j] (1024 x 512 bf16): r -> sg=r>>5, h=(r>>4)&1,
//   p=(r>>1)&7, ri=r&1, f=sg*8+p;  A2[r][j] = kern[ri*513+f][2j+h]
// blocks [256, 1284): half-rate reflect-padded signals
//   Se[b][m] = bf16(xpad[b][2m]) ,  So[b][m] = bf16(xpad[b][2m+1])
#define NA2_BLK 256     // 1024*512/8/256
#define NS2_BLK 1028    // 16*131584/8/256
__global__ __launch_bounds__(256) void prep_all(const float* __restrict__ kern,
                                                const float* __restrict__ sig,
                                                unsigned short* __restrict__ A2,
                                                unsigned short* __restrict__ Se,
                                                unsigned short* __restrict__ So) {
  if (blockIdx.x < NA2_BLK) {
    size_t i8 = ((size_t)blockIdx.x * 256 + threadIdx.x) * 8;
    int r = (int)(i8 >> 9);
    int j0 = (int)(i8 & 511);
    int sg = r >> 5, h = (r >> 4) & 1, p = (r >> 1) & 7, ri = r & 1;
    int f = sg * 8 + p;
    const float* s = kern + ((size_t)(ri * FB + f) << 10) + 2 * j0 + h;
    short8 v;
#pragma unroll
    for (int e = 0; e < 8; ++e) v[e] = (short)f2bf(s[2 * e]);
    *(short8*)(A2 + i8) = v;
  } else {
    size_t i8 = ((size_t)(blockIdx.x - NA2_BLK) * 256 + threadIdx.x) * 8;
    int b = (int)(i8 / HSIG);
    int m0 = (int)(i8 - (size_t)b * HSIG);
    const float* sb = sig + (size_t)b * SIGLEN;
    short8 ve, vo;
#pragma unroll
    for (int e = 0; e < 8; ++e) {
      int m = m0 + e;
      int je = 2 * m - 512;
      je = (je < 0) ? -je : je;
      je = (je >= SIGLEN) ? (2 * SIGLEN - 2 - je) : je;
      int jo = 2 * m - 511;
      jo = (jo < 0) ? -jo : jo;
      jo = (jo >= SIGLEN) ? (2 * SIGLEN - 2 - jo) : jo;
      ve[e] = (short)f2bf(sb[je]);
      vo[e] = (short)f2bf(sb[jo]);
    }
    *(short8*)(Se + (size_t)b * HSIG + m0) = ve;
    *(short8*)(So + (size_t)b * HSIG + m0) = vo;
  }
}

// async 16B global->LDS. LDS dest is wave-uniform; HW adds lane*16.
__device__ __forceinline__ void async16(void* lds, const void* g) {
  __builtin_amdgcn_global_load_lds(
      (const __attribute__((address_space(1))) u32*)g,
      (__attribute__((address_space(3))) u32*)lds, 16, 0, 0);
}

// ---- main GEMM ----
// 512 thr = 8 waves: wr = wid>>2 (M half, 128 rows), wc = wid&3 (N quarter, 64).
// LDS rows = 64B; involutive swizzle p = q ^ (((q>>7)&3)<<4) (R9: 0 conflicts).
__global__ __launch_bounds__(512, 2) void stft_mm(const unsigned short* __restrict__ A2,
                                                  const unsigned short* __restrict__ Se,
                                                  const unsigned short* __restrict__ So,
                                                  float* __restrict__ out) {
  extern __shared__ char smem[];

  const int tid = threadIdx.x;
  const int lane = tid & 63;
  const int wid = tid >> 6;
  const int wr = wid >> 2;   // 0..1
  const int wc = wid & 3;    // 0..3
  const int lr = lane & 15;
  const int g16 = lane >> 4;

  // bijective XCD-chunk swizzle: nwg = 256 = 8 * 32
  const int bid = blockIdx.x;
  const int wg = (bid & 7) * 32 + (bid >> 3);
  const int mt = wg & 3;
  const int r2 = wg >> 2;
  const int nt = r2 & 3;
  const int b  = r2 >> 2;

  const int c0 = mt * 256;   // A-row tile base (0..768)
  const int t0 = nt * 256;   // frame tile base (0..768)

  const char* Ab  = (const char*)A2;
  const char* SeB = (const char*)(Se + (size_t)b * HSIG);
  const char* SoB = (const char*)(So + (size_t)b * HSIG);

  // Stage K-tile kt -> slot s: A 1024 granules + Be 1024 + Bo 1024 (6/thread).
  // A row stride 1024B; B row stride 256B (half-rate hop = 128 samples).
#define STAGE(kt, s)                                                           \
  {                                                                            \
    char* dst = smem + (s) * SLOT_BYTES;                                       \
    _Pragma("unroll") for (int j = 0; j < 2; ++j) {                            \
      const int G0 = j * 512 + wid * 64;                                       \
      u32 p = (u32)(G0 + lane) * 16u;                                          \
      u32 q = p ^ (((p >> 7) & 3u) << 4);                                      \
      async16(dst + (size_t)G0 * 16u,                                          \
              Ab + ((size_t)(c0 + (int)(q >> 6)) << 10) + (kt) * 64 + (q & 63u)); \
    }                                                                          \
    _Pragma("unroll") for (int j = 0; j < 2; ++j) {                            \
      const int G0 = j * 512 + wid * 64;                                       \
      u32 p = (u32)(G0 + lane) * 16u;                                          \
      u32 q = p ^ (((p >> 7) & 3u) << 4);                                      \
      async16(dst + A_BYTES + (size_t)G0 * 16u,                                \
              SeB + ((size_t)(t0 + (int)(q >> 6)) << 8) + (kt) * 64 + (q & 63u)); \
    }                                                                          \
    _Pragma("unroll") for (int j = 0; j < 2; ++j) {                            \
      const int G0 = j * 512 + wid * 64;                                       \
      u32 p = (u32)(G0 + lane) * 16u;                                          \
      u32 q = p ^ (((p >> 7) & 3u) << 4);                                      \
      async16(dst + 2 * A_BYTES + (size_t)G0 * 16u,                            \
              SoB + ((size_t)(t0 + (int)(q >> 6)) << 8) + (kt) * 64 + (q & 63u)); \
    }                                                                          \
  }

  STAGE(0, 0)
  asm volatile("s_waitcnt vmcnt(0)" ::: "memory");
  __syncthreads();

  // per-lane swizzled read offsets (loop-invariant)
  u32 pa[8], pb[4];
#pragma unroll
  for (int mi = 0; mi < 8; ++mi) {
    u32 q = (u32)((wr * 128 + mi * 16 + lr) * 64 + g16 * 16);
    pa[mi] = q ^ (((q >> 7) & 3u) << 4);
  }
#pragma unroll
  for (int ni = 0; ni < 4; ++ni) {
    u32 q = (u32)((wc * 64 + ni * 16 + lr) * 64 + g16 * 16);
    pb[ni] = q ^ (((q >> 7) & 3u) << 4);
  }

  f32x4 acc[8][4] = {};

#pragma unroll
  for (int k = 0; k < NKT; ++k) {
    const char* As = smem + (k & 1) * SLOT_BYTES;
    // stage k+1 into the other slot (its readers finished before barrier k-1)
    if (k + 1 < NKT) STAGE(k + 1, (k + 1) & 1)

    short8 af[8], be[4], bo[4];
#pragma unroll
    for (int mi = 0; mi < 8; ++mi) af[mi] = *(const short8*)(As + pa[mi]);
#pragma unroll
    for (int ni = 0; ni < 4; ++ni) {
      be[ni] = *(const short8*)(As + A_BYTES + pb[ni]);
      bo[ni] = *(const short8*)(As + 2 * A_BYTES + pb[ni]);
    }

    // mi even -> E rows x Be;  mi odd -> O~ rows x Bo  (32 MFMA)
#pragma unroll
    for (int mi = 0; mi < 8; mi += 2)
#pragma unroll
      for (int ni = 0; ni < 4; ++ni) {
        acc[mi][ni] = __builtin_amdgcn_mfma_f32_16x16x32_bf16(
            af[mi], be[ni], acc[mi][ni], 0, 0, 0);
        acc[mi + 1][ni] = __builtin_amdgcn_mfma_f32_16x16x32_bf16(
            af[mi + 1], bo[ni], acc[mi + 1][ni], 0, 0, 0);
      }

    if (k + 1 < NKT) {
      asm volatile("s_waitcnt vmcnt(0)" ::: "memory");
      __syncthreads();
    }
  }
#undef STAGE

  // ---- butterfly epilogue ----
  // E-row (mi even): row = c0 + wr*128 + mi*16 + g16*4 + r,  pairs r=(0,1),(2,3)
  // f = (row>>5)*8 + ((row>>1)&7); O~ of the same f sits in acc[mi+1] same lane.
  // out[f]    = (Ere+Ore, Eim+Oim);  out[512-f] = (Ere-Ore, Oim-Eim)
#pragma unroll
  for (int mi = 0; mi < 8; mi += 2) {
    const int rowb = c0 + wr * 128 + mi * 16 + g16 * 4;
    const int F0 = ((rowb >> 5) << 3) + ((rowb >> 1) & 7);   // 0..254 even-pair base
#pragma unroll
    for (int ni = 0; ni < 4; ++ni) {
      const int t = t0 + wc * 64 + ni * 16 + lr;             // < 1024
      const f32x4 E = acc[mi][ni];
      const f32x4 O = acc[mi + 1][ni];
#pragma unroll
      for (int h = 0; h < 2; ++h) {                          // bins F0, F0+1
        const int f = F0 + h;
        const float Ere = E[2 * h], Eim = E[2 * h + 1];
        const float Ore = O[2 * h], Oim = O[2 * h + 1];
        *(float2*)(out + ((((size_t)b * FB + f) * NT + t) << 1)) =
            make_float2(Ere + Ore, Eim + Oim);
        *(float2*)(out + ((((size_t)b * FB + (512 - f)) * NT + t) << 1)) =
            make_float2(Ere - Ore, Oim - Eim);
      }
    }
  }
}

// ---- edge kernel (f32 direct): f=256 all t (16*1025 waves), then t=1024 for
// f=0..512 (16*513 waves). One wave per (f,t), both ri rows. ----
__global__ __launch_bounds__(256) void stft_edge(const float* __restrict__ kern,
                                                 const float* __restrict__ sig,
                                                 float* __restrict__ out) {
  const int wv = blockIdx.x * 4 + (threadIdx.x >> 6);
  const int lane = threadIdx.x & 63;
  int b, f, t;
  if (wv < NBATCH * NT) {
    b = wv / NT; t = wv - b * NT; f = 256;
  } else {
    int u = wv - NBATCH * NT;
    b = u / FB; f = u - b * FB; t = NT - 1;
  }
  const float* r0 = kern + ((size_t)f << 10);
  const float* r1 = kern + ((size_t)(FB + f) << 10);
  const float* sb = sig + (size_t)b * SIGLEN;
  const int base = t * HOP - 512;
  float d0 = 0.f, d1 = 0.f;
  if (t >= 2 && t <= 1022) {   // interior: no reflection, vectorized
    const float4* x4 = (const float4*)(sb + base + lane * 16);
    const float4* a4 = (const float4*)(r0 + lane * 16);
    const float4* b4 = (const float4*)(r1 + lane * 16);
#pragma unroll
    for (int q = 0; q < 4; ++q) {
      float4 x = x4[q], a = a4[q], c = b4[q];
      d0 += a.x * x.x + a.y * x.y + a.z * x.z + a.w * x.w;
      d1 += c.x * x.x + c.y * x.y + c.z * x.z + c.w * x.w;
    }
  } else {
#pragma unroll 4
    for (int e = 0; e < 16; ++e) {
      int n = lane * 16 + e;
      int j = base + n;
      j = (j < 0) ? -j : j;
      j = (j >= SIGLEN) ? (2 * SIGLEN - 2 - j) : j;
      float x = sb[j];
      d0 += r0[n] * x;
      d1 += r1[n] * x;
    }
  }
#pragma unroll
  for (int m = 32; m; m >>= 1) {
    d0 += __shfl_xor(d0, m);
    d1 += __shfl_xor(d1, m);
  }
  if (lane == 0)
    *(float2*)(out + ((((size_t)b * FB + f) * NT + t) << 1)) = make_float2(d0, d1);
}

extern "C" void kernel_launch(void* const* d_in, const int* in_sizes, int n_in,
                              void* d_out, int out_size, void* d_ws, size_t ws_size,
                              hipStream_t stream) {
  const float* sig = (const float*)d_in[0];    // (16, 262144) f32
  const float* kern = (const float*)d_in[1];   // (1026, 1024) f32
  float* out = (float*)d_out;                  // (16, 513, 1025, 2) f32

  unsigned short* wsA2 = (unsigned short*)d_ws;            // 1024*512   bf16
  unsigned short* wsSe = wsA2 + (size_t)1024 * 512;        // 16*131584  bf16
  unsigned short* wsSo = wsSe + (size_t)NBATCH * HSIG;     // 16*131584  bf16
  // ws use: (524288 + 2*2105344)*2 = 9,469,952 bytes

  (void)hipFuncSetAttribute((const void*)stft_mm,
                            hipFuncAttributeMaxDynamicSharedMemorySize, LDS_BYTES);

  prep_all<<<dim3(NA2_BLK + NS2_BLK), 256, 0, stream>>>(kern, sig, wsA2, wsSe, wsSo);
  stft_mm<<<dim3(256), 512, LDS_BYTES, stream>>>(wsA2, wsSe, wsSo, out);
  // edge waves: 16*1025 + 16*513 = 24608 = 6152 blocks * 4 waves (exact)
  stft_edge<<<dim3((NBATCH * NT + NBATCH * FB) / 4), 256, 0, stream>>>(kern, sig, out);
}